// Round 3
// baseline (446.726 us; speedup 1.0000x reference)
//
#include <hip/hip_runtime.h>

// out = clip(x + laplace_noise * mask, 0, 1), element-wise over
// N = 256*3*224*224 = 38,535,168 fp32 elements. Memory-bound streaming.
//
// v3: persistent grid-stride. Baseline (1 float4/thread, 37,632 blocks)
// ran at 4.1 ns/block = the CP workgroup-launch rate; v2 showed extra
// per-wave MLP doesn't help (traffic counters identical, 9% slower).
// So: grid = 1792 blocks (7/CU, all resident from t=0, zero churn),
// each wave does 21 grid-stride iterations of the baseline's exact
// per-instruction access pattern (contiguous 1KB/wave/stream).
// 1792 * 256 * 21 = 9,633,792 = n4 exactly — no tail, perfect balance.
// Plain stores (v2 showed NT store has zero cache effect here).

typedef float f4 __attribute__((ext_vector_type(4)));

constexpr int BLOCK = 256;
constexpr int GRID  = 1792;   // 7 blocks/CU * 256 CUs

__global__ __launch_bounds__(BLOCK) void rrn_clip_kernel(
    const f4* __restrict__ x,
    const f4* __restrict__ lap,
    const f4* __restrict__ mask,
    f4* __restrict__ out,
    int n4)
{
    const int stride = GRID * BLOCK;                    // 458,752 float4s
    int i = blockIdx.x * BLOCK + threadIdx.x;

#pragma unroll 2
    for (; i < n4; i += stride) {
        f4 xv = x[i];
        f4 lv = lap[i];
        f4 mv = mask[i];

        f4 o;
        o.x = fminf(fmaxf(fmaf(lv.x, mv.x, xv.x), 0.0f), 1.0f);
        o.y = fminf(fmaxf(fmaf(lv.y, mv.y, xv.y), 0.0f), 1.0f);
        o.z = fminf(fmaxf(fmaf(lv.z, mv.z, xv.z), 0.0f), 1.0f);
        o.w = fminf(fmaxf(fmaf(lv.w, mv.w, xv.w), 0.0f), 1.0f);

        out[i] = o;
    }
}

extern "C" void kernel_launch(void* const* d_in, const int* in_sizes, int n_in,
                              void* d_out, int out_size, void* d_ws, size_t ws_size,
                              hipStream_t stream)
{
    const f4* x    = (const f4*)d_in[0];
    // d_in[1] = eps (scalar) — unused; Bernoulli keep-prob already in mask.
    const f4* lap  = (const f4*)d_in[2];
    const f4* mask = (const f4*)d_in[3];
    f4* out        = (f4*)d_out;

    int n  = out_size;           // 38,535,168 — divisible by 4
    int n4 = n >> 2;             // 9,633,792 float4 elements

    rrn_clip_kernel<<<GRID, BLOCK, 0, stream>>>(x, lap, mask, out, n4);
}

// Round 4
// 422.921 us; speedup vs baseline: 1.0563x; 1.0563x over previous
//
#include <hip/hip_runtime.h>

// out = clip(x + laplace_noise * mask, 0, 1), element-wise over
// N = 256*3*224*224 = 38,535,168 fp32 elements. Memory-bound streaming.
//
// v4: DISCRIMINATOR EXPERIMENT — non-temporal loads on all 3 input streams.
// Evidence so far: three execution structures (tiny blocks / ILP=4 /
// persistent) all give 155-168 us with byte-identical counters
// (FETCH=225.8MB = 50% L3 hit, WRITE=150.5MB). No tier is saturated
// (HBM 2.49 of 6.3 TB/s, L2 <<34.5, VALU 1.5%) yet aggregate caps at
// ~4.0 TB/s. Hypothesis: the L3 install/hit path (231 MB of new lines
// installed+evicted per dispatch) is the serializer. NT loads bypass
// cache allocation -> pure HBM streaming, which has 6.3 TB/s headroom
// for the full 616 MB working set.
//   - If right: FETCH -> ~460MB, dur -> ~110-130 us.
//   - If HBM-efficiency is the true wall: dur worsens -> revert, roofline.
//   - If NT doesn't propagate: counters flat -> no-op, roofline call strengthens.
// Structure is the round-0 baseline (fastest so far): 1 float4/thread.
// Plain stores (NT store proven neutral in v2).

typedef float f4 __attribute__((ext_vector_type(4)));

constexpr int BLOCK = 256;

__global__ __launch_bounds__(BLOCK) void rrn_clip_kernel(
    const f4* __restrict__ x,
    const f4* __restrict__ lap,
    const f4* __restrict__ mask,
    f4* __restrict__ out,
    int n4)
{
    int i = blockIdx.x * BLOCK + threadIdx.x;
    if (i >= n4) return;

    f4 xv = __builtin_nontemporal_load(&x[i]);
    f4 lv = __builtin_nontemporal_load(&lap[i]);
    f4 mv = __builtin_nontemporal_load(&mask[i]);

    f4 o;
    o.x = fminf(fmaxf(fmaf(lv.x, mv.x, xv.x), 0.0f), 1.0f);
    o.y = fminf(fmaxf(fmaf(lv.y, mv.y, xv.y), 0.0f), 1.0f);
    o.z = fminf(fmaxf(fmaf(lv.z, mv.z, xv.z), 0.0f), 1.0f);
    o.w = fminf(fmaxf(fmaf(lv.w, mv.w, xv.w), 0.0f), 1.0f);

    out[i] = o;
}

extern "C" void kernel_launch(void* const* d_in, const int* in_sizes, int n_in,
                              void* d_out, int out_size, void* d_ws, size_t ws_size,
                              hipStream_t stream)
{
    const f4* x    = (const f4*)d_in[0];
    // d_in[1] = eps (scalar) — unused; Bernoulli keep-prob already in mask.
    const f4* lap  = (const f4*)d_in[2];
    const f4* mask = (const f4*)d_in[3];
    f4* out        = (f4*)d_out;

    int n  = out_size;           // 38,535,168 — divisible by 4
    int n4 = n >> 2;             // 9,633,792 float4 elements

    const int grid = (n4 + BLOCK - 1) / BLOCK;   // 37,632 blocks

    rrn_clip_kernel<<<grid, BLOCK, 0, stream>>>(x, lap, mask, out, n4);
}

// Round 5
// 418.020 us; speedup vs baseline: 1.0687x; 1.0117x over previous
//
#include <hip/hip_runtime.h>

// out = clip(x + laplace_noise * mask, 0, 1), element-wise over
// N = 256*3*224*224 = 38,535,168 fp32 elements. Memory-bound streaming.
//
// v5: v4 (NT loads, -28%: 155->111us) + NT stores. v4 taught us the nt
// flag does NOT change L3 behavior (FETCH identical, still 50% hit) but
// removes per-XCD L2 install/evict thrash for streaming lines -> combined
// effective throughput 3.98 -> 5.55 TB/s. The write stream (150.5 MB,
// never re-read) still allocates into L2; nt-store is the same fix on the
// write path. (v2's "NT store neutral" was confounded: measured without
// NT loads, read-thrash dominating, plus an ILP-4 structure change.)
// Predict: dur 111 -> ~100-105us if store-install matters; flat if the
// store path is already non-allocating -> then we're at 88% of the copy
// ceiling and call roofline.

typedef float f4 __attribute__((ext_vector_type(4)));

constexpr int BLOCK = 256;

__global__ __launch_bounds__(BLOCK) void rrn_clip_kernel(
    const f4* __restrict__ x,
    const f4* __restrict__ lap,
    const f4* __restrict__ mask,
    f4* __restrict__ out,
    int n4)
{
    int i = blockIdx.x * BLOCK + threadIdx.x;
    if (i >= n4) return;

    f4 xv = __builtin_nontemporal_load(&x[i]);
    f4 lv = __builtin_nontemporal_load(&lap[i]);
    f4 mv = __builtin_nontemporal_load(&mask[i]);

    f4 o;
    o.x = fminf(fmaxf(fmaf(lv.x, mv.x, xv.x), 0.0f), 1.0f);
    o.y = fminf(fmaxf(fmaf(lv.y, mv.y, xv.y), 0.0f), 1.0f);
    o.z = fminf(fmaxf(fmaf(lv.z, mv.z, xv.z), 0.0f), 1.0f);
    o.w = fminf(fmaxf(fmaf(lv.w, mv.w, xv.w), 0.0f), 1.0f);

    __builtin_nontemporal_store(o, &out[i]);
}

extern "C" void kernel_launch(void* const* d_in, const int* in_sizes, int n_in,
                              void* d_out, int out_size, void* d_ws, size_t ws_size,
                              hipStream_t stream)
{
    const f4* x    = (const f4*)d_in[0];
    // d_in[1] = eps (scalar) — unused; Bernoulli keep-prob already in mask.
    const f4* lap  = (const f4*)d_in[2];
    const f4* mask = (const f4*)d_in[3];
    f4* out        = (f4*)d_out;

    int n  = out_size;           // 38,535,168 — divisible by 4
    int n4 = n >> 2;             // 9,633,792 float4 elements

    const int grid = (n4 + BLOCK - 1) / BLOCK;   // 37,632 blocks

    rrn_clip_kernel<<<grid, BLOCK, 0, stream>>>(x, lap, mask, out, n4);
}